// Round 1
// baseline (6208.161 us; speedup 1.0000x reference)
//
#include <hip/hip_runtime.h>
#include <math.h>

// ---------------------------------------------------------------------------
// DeepSeek MLHA attention, fp32 baseline pipeline.
// B=2, T=2048, hidden=2048, NH=16, NKV=4, HD=128, latent=256, kv_dim=512.
// ---------------------------------------------------------------------------

#define BM 64
#define BN 64
#define BK 16

// --- RoPE cos/sin table: (T, 64) each, computed in double for safety -------
__global__ __launch_bounds__(256) void rope_table(float* __restrict__ cost,
                                                  float* __restrict__ sint,
                                                  int T) {
  int idx = blockIdx.x * 256 + threadIdx.x;
  if (idx >= T * 64) return;
  int t = idx >> 6, j = idx & 63;
  double invf = pow(10000.0, -(double)j / 64.0);
  double ang = (double)t * invf;
  cost[idx] = (float)cos(ang);
  sint[idx] = (float)sin(ang);
}

// --- NT GEMM: C[M,N] = A[M,K] @ W[N,K]^T  (rows dot rows) ------------------
// 64x64 tile, BK=16, 256 threads, 4x4 per thread. All dims % 64 / % 16 == 0.
__global__ __launch_bounds__(256) void gemm_nt(const float* __restrict__ A,
                                               const float* __restrict__ W,
                                               float* __restrict__ C,
                                               int M, int N, int K) {
  __shared__ float As[BM][BK + 1];
  __shared__ float Ws[BN][BK + 1];
  int tid = threadIdx.x;
  int tx = tid & 15, ty = tid >> 4;
  int m0 = blockIdx.y * BM, n0 = blockIdx.x * BN;
  int r = tid >> 2, c4 = (tid & 3) * 4;
  float acc[4][4] = {};
  for (int k0 = 0; k0 < K; k0 += BK) {
    float4 a4 = *(const float4*)(A + (size_t)(m0 + r) * K + k0 + c4);
    float4 w4 = *(const float4*)(W + (size_t)(n0 + r) * K + k0 + c4);
    As[r][c4 + 0] = a4.x; As[r][c4 + 1] = a4.y;
    As[r][c4 + 2] = a4.z; As[r][c4 + 3] = a4.w;
    Ws[r][c4 + 0] = w4.x; Ws[r][c4 + 1] = w4.y;
    Ws[r][c4 + 2] = w4.z; Ws[r][c4 + 3] = w4.w;
    __syncthreads();
#pragma unroll
    for (int kk = 0; kk < BK; ++kk) {
      float a[4], b[4];
#pragma unroll
      for (int i = 0; i < 4; ++i) a[i] = As[ty * 4 + i][kk];
#pragma unroll
      for (int j = 0; j < 4; ++j) b[j] = Ws[tx * 4 + j][kk];
#pragma unroll
      for (int i = 0; i < 4; ++i)
#pragma unroll
        for (int j = 0; j < 4; ++j) acc[i][j] += a[i] * b[j];
    }
    __syncthreads();
  }
#pragma unroll
  for (int i = 0; i < 4; ++i)
#pragma unroll
    for (int j = 0; j < 4; ++j)
      C[(size_t)(m0 + ty * 4 + i) * N + n0 + tx * 4 + j] = acc[i][j];
}

// --- In-place RoPE. buf: (B*T, nheads*128). Thread owns pair (d, d+64). ----
__global__ __launch_bounds__(256) void rope_apply(float* __restrict__ buf,
                                                  int nheads, int T,
                                                  const float* __restrict__ cost,
                                                  const float* __restrict__ sint) {
  int idx = blockIdx.x * 256 + threadIdx.x;
  int d = idx & 63;
  int rest = idx >> 6;
  int h = rest % nheads;
  int bt = rest / nheads;
  int t = bt & (T - 1);
  float* p = buf + (size_t)bt * nheads * 128 + h * 128;
  float c = cost[t * 64 + d], s = sint[t * 64 + d];
  float x0 = p[d], x1 = p[d + 64];
  p[d]      = x0 * c - x1 * s;
  p[d + 64] = x1 * c + x0 * s;
}

// --- Flash attention: one wave (64 lanes) per query row. -------------------
// q: (B*T, 2048) at [bt*2048 + h*128 + d]; k,v: (B*T, 512) at [bt*512+kvh*128+d]
__global__ __launch_bounds__(256) void flash_rowwave(const float* __restrict__ q,
                                                     const float* __restrict__ k,
                                                     const float* __restrict__ v,
                                                     float* __restrict__ o) {
  int gwid = (blockIdx.x * 256 + threadIdx.x) >> 6;
  int lane = threadIdx.x & 63;
  int t = gwid & 2047;        // T = 2048
  int bh = gwid >> 11;
  int h = bh & 15;            // NH = 16
  int b = bh >> 4;
  int kvh = h >> 2;           // rep = 4 -> kv head = h/4
  int d0 = lane * 2;
  size_t qoff = ((size_t)(b * 2048 + t)) * 2048 + h * 128;
  const float scale = 0.088388347648318447f;  // 1/sqrt(128)
  float2 q2 = *(const float2*)(q + qoff + d0);
  float qx = q2.x * scale, qy = q2.y * scale;
  const float* kp = k + (size_t)b * 2048 * 512 + kvh * 128 + d0;
  const float* vp = v + (size_t)b * 2048 * 512 + kvh * 128 + d0;
  float m = -INFINITY, l = 0.f, a0 = 0.f, a1 = 0.f;
  for (int kk = 0; kk <= t; ++kk) {
    float2 k2 = *(const float2*)(kp + (size_t)kk * 512);
    float part = qx * k2.x + qy * k2.y;
#pragma unroll
    for (int off = 32; off > 0; off >>= 1) part += __shfl_xor(part, off);
    float mn = fmaxf(m, part);
    float corr = __expf(m - mn);
    float p = __expf(part - mn);
    float2 v2 = *(const float2*)(vp + (size_t)kk * 512);
    l = l * corr + p;
    a0 = a0 * corr + p * v2.x;
    a1 = a1 * corr + p * v2.y;
    m = mn;
  }
  float inv = 1.f / l;
  o[qoff + d0]     = a0 * inv;
  o[qoff + d0 + 1] = a1 * inv;
}

// ---------------------------------------------------------------------------
extern "C" void kernel_launch(void* const* d_in, const int* in_sizes, int n_in,
                              void* d_out, int out_size, void* d_ws, size_t ws_size,
                              hipStream_t stream) {
  const float* x   = (const float*)d_in[0];  // (B,T,2048)
  const float* wq  = (const float*)d_in[1];  // (2048,2048)
  const float* wkv = (const float*)d_in[2];  // (256,2048)
  const float* wk  = (const float*)d_in[3];  // (512,256)
  const float* wv  = (const float*)d_in[4];  // (512,256)
  const float* wo  = (const float*)d_in[5];  // (2048,2048)
  float* out = (float*)d_out;
  float* ws  = (float*)d_ws;

  const int B = 2, T = 2048, H = 2048, NH = 16, NKV = 4, LAT = 256, KVD = 512;
  const int BT = B * T;  // 4096

  size_t off = 0;
  float* q    = ws + off; off += (size_t)BT * H;    // 8,388,608
  float* kvl  = ws + off; off += (size_t)BT * LAT;  // 1,048,576
  float* kbuf = ws + off; off += (size_t)BT * KVD;  // 2,097,152
  float* vbuf = ws + off; off += (size_t)BT * KVD;  // 2,097,152
  float* atto = ws + off; off += (size_t)BT * H;    // 8,388,608
  float* cost = ws + off; off += (size_t)T * 64;
  float* sint = ws + off; off += (size_t)T * 64;
  // total ~22.3M floats ~= 85 MiB

  // 1. RoPE table
  rope_table<<<(T * 64 + 255) / 256, 256, 0, stream>>>(cost, sint, T);

  // 2. Projections
  gemm_nt<<<dim3(H / BN, BT / BM), 256, 0, stream>>>(x, wq, q, BT, H, H);
  gemm_nt<<<dim3(LAT / BN, BT / BM), 256, 0, stream>>>(x, wkv, kvl, BT, LAT, H);
  gemm_nt<<<dim3(KVD / BN, BT / BM), 256, 0, stream>>>(kvl, wk, kbuf, BT, KVD, LAT);
  gemm_nt<<<dim3(KVD / BN, BT / BM), 256, 0, stream>>>(kvl, wv, vbuf, BT, KVD, LAT);

  // 3. RoPE (in place)
  rope_apply<<<(BT * NH * 64) / 256, 256, 0, stream>>>(q, NH, T, cost, sint);
  rope_apply<<<(BT * NKV * 64) / 256, 256, 0, stream>>>(kbuf, NKV, T, cost, sint);

  // 4. Attention (one wave per query row, 65536 waves)
  flash_rowwave<<<(B * NH * T) / 4, 256, 0, stream>>>(q, kbuf, vbuf, atto);

  // 5. Output projection
  gemm_nt<<<dim3(H / BN, BT / BM), 256, 0, stream>>>(atto, wo, out, BT, H, H);
}

// Round 2
// 1997.852 us; speedup vs baseline: 3.1074x; 3.1074x over previous
//
#include <hip/hip_runtime.h>
#include <math.h>

// ---------------------------------------------------------------------------
// DeepSeek MLHA attention. Round 2: MFMA bf16 flash attention.
// B=2, T=2048, hidden=2048, NH=16, NKV=4, HD=128, latent=256, kv_dim=512.
// ---------------------------------------------------------------------------

#define BM 64
#define BN 64
#define BK 16

typedef short bf16x8 __attribute__((ext_vector_type(8)));
typedef float f32x4 __attribute__((ext_vector_type(4)));

__device__ __forceinline__ unsigned short f2bf(float x) {
  union { float f; unsigned int u; } q; q.f = x;
  unsigned int u = q.u;
  u += 0x7FFFu + ((u >> 16) & 1u);   // round-to-nearest-even
  return (unsigned short)(u >> 16);
}

// --- RoPE cos/sin table: (T, 64) each, double precision, runs once ---------
__global__ __launch_bounds__(256) void rope_table(float* __restrict__ cost,
                                                  float* __restrict__ sint,
                                                  int T) {
  int idx = blockIdx.x * 256 + threadIdx.x;
  if (idx >= T * 64) return;
  int t = idx >> 6, j = idx & 63;
  double invf = pow(10000.0, -(double)j / 64.0);
  double ang = (double)t * invf;
  cost[idx] = (float)cos(ang);
  sint[idx] = (float)sin(ang);
}

// --- NT GEMM: C[M,N] = A[M,K] @ W[N,K]^T  (fp32, 64x64 tile) ---------------
__global__ __launch_bounds__(256) void gemm_nt(const float* __restrict__ A,
                                               const float* __restrict__ W,
                                               float* __restrict__ C,
                                               int M, int N, int K) {
  __shared__ float As[BM][BK + 1];
  __shared__ float Ws[BN][BK + 1];
  int tid = threadIdx.x;
  int tx = tid & 15, ty = tid >> 4;
  int m0 = blockIdx.y * BM, n0 = blockIdx.x * BN;
  int r = tid >> 2, c4 = (tid & 3) * 4;
  float acc[4][4] = {};
  for (int k0 = 0; k0 < K; k0 += BK) {
    float4 a4 = *(const float4*)(A + (size_t)(m0 + r) * K + k0 + c4);
    float4 w4 = *(const float4*)(W + (size_t)(n0 + r) * K + k0 + c4);
    As[r][c4 + 0] = a4.x; As[r][c4 + 1] = a4.y;
    As[r][c4 + 2] = a4.z; As[r][c4 + 3] = a4.w;
    Ws[r][c4 + 0] = w4.x; Ws[r][c4 + 1] = w4.y;
    Ws[r][c4 + 2] = w4.z; Ws[r][c4 + 3] = w4.w;
    __syncthreads();
#pragma unroll
    for (int kk = 0; kk < BK; ++kk) {
      float a[4], b[4];
#pragma unroll
      for (int i = 0; i < 4; ++i) a[i] = As[ty * 4 + i][kk];
#pragma unroll
      for (int j = 0; j < 4; ++j) b[j] = Ws[tx * 4 + j][kk];
#pragma unroll
      for (int i = 0; i < 4; ++i)
#pragma unroll
        for (int j = 0; j < 4; ++j) acc[i][j] += a[i] * b[j];
    }
    __syncthreads();
  }
#pragma unroll
  for (int i = 0; i < 4; ++i)
#pragma unroll
    for (int j = 0; j < 4; ++j)
      C[(size_t)(m0 + ty * 4 + i) * N + n0 + tx * 4 + j] = acc[i][j];
}

// --- RoPE + bf16 convert. src fp32 (B*T, nheads*128) -> dst bf16. ----------
__global__ __launch_bounds__(256) void rope_bf16(const float* __restrict__ src,
                                                 unsigned short* __restrict__ dst,
                                                 int nheads, int T,
                                                 const float* __restrict__ cost,
                                                 const float* __restrict__ sint,
                                                 float scale) {
  int idx = blockIdx.x * 256 + threadIdx.x;
  int d = idx & 63;
  int rest = idx >> 6;
  int h = rest % nheads;
  int bt = rest / nheads;
  int t = bt & (T - 1);
  size_t base = (size_t)bt * nheads * 128 + h * 128;
  const float* p = src + base;
  unsigned short* pd = dst + base;
  float c = cost[t * 64 + d], s = sint[t * 64 + d];
  float x0 = p[d], x1 = p[d + 64];
  pd[d]      = f2bf((x0 * c - x1 * s) * scale);
  pd[d + 64] = f2bf((x1 * c + x0 * s) * scale);
}

// --- plain fp32 -> bf16 convert (n multiple of 4) --------------------------
__global__ __launch_bounds__(256) void conv_bf16(const float* __restrict__ src,
                                                 unsigned short* __restrict__ dst,
                                                 int n) {
  int i = (blockIdx.x * 256 + threadIdx.x) * 4;
  if (i >= n) return;
  float4 f = *(const float4*)(src + i);
  ushort4 o;
  o.x = f2bf(f.x); o.y = f2bf(f.y); o.z = f2bf(f.z); o.w = f2bf(f.w);
  *(ushort4*)(dst + i) = o;
}

// --- MFMA flash attention --------------------------------------------------
// One wave per 16-query tile. KV tiles of 32 keys.
// qb: (B*T, 2048) bf16 (scale folded); kb/vb: (B*T, 512) bf16.
// o (atto): (B*T, 2048) fp32.
__global__ __launch_bounds__(256) void attn_mfma(const unsigned short* __restrict__ qb,
                                                 const unsigned short* __restrict__ kb,
                                                 const unsigned short* __restrict__ vb,
                                                 float* __restrict__ o) {
  __shared__ unsigned short plds[4][16][32];
  int w = threadIdx.x >> 6, lane = threadIdx.x & 63;
  int gw = blockIdx.x * 4 + w;
  int qt = gw & 127;          // T/16 = 128 q-tiles
  int bh = gw >> 7;
  int h = bh & 15, b = bh >> 4;
  int kvh = h >> 2;
  int q0 = qt * 16;
  int g = lane >> 4, c = lane & 15;

  // Q A-frags: qa[kc][j] = Q[q0+c][kc*32 + g*8 + j]
  const unsigned short* qrow = qb + ((size_t)(b * 2048 + q0 + c)) * 2048 + h * 128;
  bf16x8 qa[4];
#pragma unroll
  for (int kc = 0; kc < 4; ++kc)
    qa[kc] = *(const bf16x8*)(qrow + kc * 32 + g * 8);

  const unsigned short* kbase = kb + (size_t)b * 2048 * 512 + kvh * 128;
  const unsigned short* vbase = vb + (size_t)b * 2048 * 512 + kvh * 128;

  f32x4 o_acc[8];
#pragma unroll
  for (int ch = 0; ch < 8; ++ch) o_acc[ch] = (f32x4){0.f, 0.f, 0.f, 0.f};
  float m[4], l[4];
#pragma unroll
  for (int r = 0; r < 4; ++r) { m[r] = -INFINITY; l[r] = 0.f; }

  int nt = (q0 + 47) >> 5;   // tiles covering keys 0 .. q0+15
  for (int ti = 0; ti < nt; ++ti) {
    int k0 = ti * 32;
    // ---- QK^T: S[q][k], two 16-col blocks ----
    f32x4 s0 = (f32x4){0.f, 0.f, 0.f, 0.f};
    f32x4 s1 = (f32x4){0.f, 0.f, 0.f, 0.f};
#pragma unroll
    for (int kc = 0; kc < 4; ++kc) {
      bf16x8 kf0 = *(const bf16x8*)(kbase + (size_t)(k0 + c) * 512 + kc * 32 + g * 8);
      bf16x8 kf1 = *(const bf16x8*)(kbase + (size_t)(k0 + 16 + c) * 512 + kc * 32 + g * 8);
      s0 = __builtin_amdgcn_mfma_f32_16x16x32_bf16(qa[kc], kf0, s0, 0, 0, 0);
      s1 = __builtin_amdgcn_mfma_f32_16x16x32_bf16(qa[kc], kf1, s1, 0, 0, 0);
    }
    // ---- causal mask + online softmax ----
    bool guard = (k0 + 31 > q0);
#pragma unroll
    for (int r = 0; r < 4; ++r) {
      int qi = q0 + g * 4 + r;
      if (guard) {
        if (k0 + c > qi)      s0[r] = -INFINITY;
        if (k0 + 16 + c > qi) s1[r] = -INFINITY;
      }
      float tv = fmaxf(s0[r], s1[r]);
#pragma unroll
      for (int off = 1; off < 16; off <<= 1) tv = fmaxf(tv, __shfl_xor(tv, off));
      float mn = fmaxf(m[r], tv);
      float corr = __expf(m[r] - mn);
      m[r] = mn;
      float p0 = __expf(s0[r] - mn);
      float p1 = __expf(s1[r] - mn);
      float rs = p0 + p1;
#pragma unroll
      for (int off = 1; off < 16; off <<= 1) rs += __shfl_xor(rs, off);
      l[r] = l[r] * corr + rs;
#pragma unroll
      for (int ch = 0; ch < 8; ++ch) o_acc[ch][r] *= corr;
      plds[w][g * 4 + r][c]      = f2bf(p0);
      plds[w][g * 4 + r][16 + c] = f2bf(p1);
    }
    // ---- PV: O[16q][128d] += P(16x32) @ V(32x128) ----
    // A-frag: P[c][g*8+j] (same LDS array -> compiler keeps DS order; wave-
    // internal lockstep, LDS pipe is in-order, no barrier needed)
    bf16x8 pa = *(const bf16x8*)(&plds[w][c][g * 8]);
#pragma unroll
    for (int ch = 0; ch < 8; ++ch) {
      const unsigned short* vcol = vbase + (size_t)(k0 + g * 8) * 512 + ch * 16 + c;
      bf16x8 vf;
#pragma unroll
      for (int j = 0; j < 8; ++j) vf[j] = (short)vcol[(size_t)j * 512];
      o_acc[ch] = __builtin_amdgcn_mfma_f32_16x16x32_bf16(pa, vf, o_acc[ch], 0, 0, 0);
    }
  }
  // ---- epilogue: O / l ----
#pragma unroll
  for (int r = 0; r < 4; ++r) {
    float inv = 1.f / l[r];
    int qi = q0 + g * 4 + r;
    float* orow = o + ((size_t)(b * 2048 + qi)) * 2048 + h * 128;
#pragma unroll
    for (int ch = 0; ch < 8; ++ch) orow[ch * 16 + c] = o_acc[ch][r] * inv;
  }
}

// ---------------------------------------------------------------------------
extern "C" void kernel_launch(void* const* d_in, const int* in_sizes, int n_in,
                              void* d_out, int out_size, void* d_ws, size_t ws_size,
                              hipStream_t stream) {
  const float* x   = (const float*)d_in[0];
  const float* wq  = (const float*)d_in[1];
  const float* wkv = (const float*)d_in[2];
  const float* wk  = (const float*)d_in[3];
  const float* wv  = (const float*)d_in[4];
  const float* wo  = (const float*)d_in[5];
  float* out = (float*)d_out;
  float* ws  = (float*)d_ws;

  const int B = 2, T = 2048, H = 2048, NH = 16, NKV = 4, LAT = 256, KVD = 512;
  const int BT = B * T;  // 4096

  size_t off = 0;
  float* q    = ws + off; off += (size_t)BT * H;    // fp32 q; later reused as atto
  float* kvl  = ws + off; off += (size_t)BT * LAT;
  float* kbuf = ws + off; off += (size_t)BT * KVD;
  float* vbuf = ws + off; off += (size_t)BT * KVD;
  float* cost = ws + off; off += (size_t)T * 64;
  float* sint = ws + off; off += (size_t)T * 64;
  unsigned short* qb = (unsigned short*)(ws + off); off += (size_t)BT * H / 2;
  unsigned short* kb = (unsigned short*)(ws + off); off += (size_t)BT * KVD / 2;
  unsigned short* vb = (unsigned short*)(ws + off); off += (size_t)BT * KVD / 2;
  float* atto = q;  // fp32 q is dead once qb exists; attn output overlays it
  // total ~19.5M floats ~= 78 MiB

  const float scale = 0.088388347648318447f;  // 1/sqrt(128)

  rope_table<<<(T * 64 + 255) / 256, 256, 0, stream>>>(cost, sint, T);

  // Projections (fp32)
  gemm_nt<<<dim3(H / BN, BT / BM), 256, 0, stream>>>(x, wq, q, BT, H, H);
  gemm_nt<<<dim3(LAT / BN, BT / BM), 256, 0, stream>>>(x, wkv, kvl, BT, LAT, H);
  gemm_nt<<<dim3(KVD / BN, BT / BM), 256, 0, stream>>>(kvl, wk, kbuf, BT, KVD, LAT);
  gemm_nt<<<dim3(KVD / BN, BT / BM), 256, 0, stream>>>(kvl, wv, vbuf, BT, KVD, LAT);

  // RoPE + bf16 (scale folded into q); V plain convert
  rope_bf16<<<(BT * NH * 64) / 256, 256, 0, stream>>>(q, qb, NH, T, cost, sint, scale);
  rope_bf16<<<(BT * NKV * 64) / 256, 256, 0, stream>>>(kbuf, kb, NKV, T, cost, sint, 1.0f);
  conv_bf16<<<(BT * KVD / 4 + 255) / 256, 256, 0, stream>>>(vbuf, vb, BT * KVD);

  // MFMA flash attention: 4096 waves, 4 per block
  attn_mfma<<<(B * NH * T / 16) / 4, 256, 0, stream>>>(qb, kb, vb, atto);

  // Output projection (fp32)
  gemm_nt<<<dim3(H / BN, BT / BM), 256, 0, stream>>>(atto, wo, out, BT, H, H);
}

// Round 4
// 756.889 us; speedup vs baseline: 8.2022x; 2.6396x over previous
//
#include <hip/hip_runtime.h>
#include <math.h>

// ---------------------------------------------------------------------------
// DeepSeek MLHA attention. Round 3 (resubmit after infra failure):
// bf16 MFMA GEMMs (m97 structure) + MFMA flash attention with transposed-V.
// B=2, T=2048, hidden=2048, NH=16, NKV=4, HD=128, latent=256, kv_dim=512.
// ---------------------------------------------------------------------------

#define AS1 __attribute__((address_space(1)))
#define AS3 __attribute__((address_space(3)))

typedef short bf16x8 __attribute__((ext_vector_type(8)));
typedef float f32x4 __attribute__((ext_vector_type(4)));

__device__ __forceinline__ unsigned short f2bf(float x) {
  union { float f; unsigned int u; } q; q.f = x;
  unsigned int u = q.u;
  u += 0x7FFFu + ((u >> 16) & 1u);   // RNE
  return (unsigned short)(u >> 16);
}
__device__ __forceinline__ float bf2f(unsigned short x) {
  union { unsigned int u; float f; } q; q.u = ((unsigned int)x) << 16;
  return q.f;
}

// --- RoPE cos/sin table: (T, 64) each, double precision ---------------------
__global__ __launch_bounds__(256) void rope_table(float* __restrict__ cost,
                                                  float* __restrict__ sint,
                                                  int T) {
  int idx = blockIdx.x * 256 + threadIdx.x;
  if (idx >= T * 64) return;
  int t = idx >> 6, j = idx & 63;
  double invf = pow(10000.0, -(double)j / 64.0);
  double ang = (double)t * invf;
  cost[idx] = (float)cos(ang);
  sint[idx] = (float)sin(ang);
}

// --- fp32 -> bf16 convert (n multiple of 4) --------------------------------
__global__ __launch_bounds__(256) void conv_bf16(const float* __restrict__ src,
                                                 unsigned short* __restrict__ dst,
                                                 int n) {
  int i = (blockIdx.x * 256 + threadIdx.x) * 4;
  if (i >= n) return;
  float4 f = *(const float4*)(src + i);
  ushort4 o;
  o.x = f2bf(f.x); o.y = f2bf(f.y); o.z = f2bf(f.z); o.w = f2bf(f.w);
  *(ushort4*)(dst + i) = o;
}

// --- bf16 MFMA NT-GEMM: C[M,N] = A[M,K] @ W[N,K]^T (fp32 accum) ------------
// m97 structure: 128x128 tile, BK=32, 4 waves, 64x64 per wave,
// global_load_lds width=16, single LDS buffer, 2 barriers per K-step.
template <bool OUT_BF16>
__global__ __launch_bounds__(256) void gemm_mfma(const unsigned short* __restrict__ A,
                                                 const unsigned short* __restrict__ W,
                                                 void* __restrict__ Cv,
                                                 int M, int N, int K) {
  __shared__ unsigned short Asl[128 * 32];
  __shared__ unsigned short Wsl[128 * 32];
  int tid = threadIdx.x;
  int w = tid >> 6, lane = tid & 63;
  int g = lane >> 4, c = lane & 15;
  int wm = w >> 1, wn = w & 1;
  int m0 = blockIdx.y * 128, n0 = blockIdx.x * 128;

  f32x4 acc[4][4] = {};

  for (int k0 = 0; k0 < K; k0 += 32) {
#pragma unroll
    for (int i = 0; i < 2; ++i) {
      int idx = i * 256 + tid;            // 0..511 -> 16B chunk of tile
      int row = idx >> 2;                 // 0..127
      int kk = (idx & 3) * 8;             // 0,8,16,24
      __builtin_amdgcn_global_load_lds(
          (const AS1 void*)(A + (size_t)(m0 + row) * K + k0 + kk),
          (AS3 void*)(Asl + ((size_t)i * 256 + (w << 6)) * 8), 16, 0, 0);
      __builtin_amdgcn_global_load_lds(
          (const AS1 void*)(W + (size_t)(n0 + row) * K + k0 + kk),
          (AS3 void*)(Wsl + ((size_t)i * 256 + (w << 6)) * 8), 16, 0, 0);
    }
    __syncthreads();   // drains vmcnt before barrier
    bf16x8 af[4], wf[4];
#pragma unroll
    for (int mi = 0; mi < 4; ++mi)
      af[mi] = *(const bf16x8*)(Asl + (wm * 64 + mi * 16 + c) * 32 + g * 8);
#pragma unroll
    for (int ni = 0; ni < 4; ++ni)
      wf[ni] = *(const bf16x8*)(Wsl + (wn * 64 + ni * 16 + c) * 32 + g * 8);
#pragma unroll
    for (int mi = 0; mi < 4; ++mi)
#pragma unroll
      for (int ni = 0; ni < 4; ++ni)
        acc[mi][ni] = __builtin_amdgcn_mfma_f32_16x16x32_bf16(af[mi], wf[ni],
                                                              acc[mi][ni], 0, 0, 0);
    __syncthreads();
  }
  // epilogue: C row = m0+wm*64+mi*16+g*4+r, col = n0+wn*64+ni*16+c
#pragma unroll
  for (int mi = 0; mi < 4; ++mi)
#pragma unroll
    for (int r = 0; r < 4; ++r) {
      size_t mrow = (size_t)(m0 + wm * 64 + mi * 16 + g * 4 + r) * N;
#pragma unroll
      for (int ni = 0; ni < 4; ++ni) {
        int n = n0 + wn * 64 + ni * 16 + c;
        if (OUT_BF16)
          ((unsigned short*)Cv)[mrow + n] = f2bf(acc[mi][ni][r]);
        else
          ((float*)Cv)[mrow + n] = acc[mi][ni][r];
      }
    }
}

// --- in-place RoPE on bf16 buffer (B*T, nheads*128), scale folded ----------
__global__ __launch_bounds__(256) void rope_ip_bf16(unsigned short* __restrict__ buf,
                                                    int nheads, int T,
                                                    const float* __restrict__ cost,
                                                    const float* __restrict__ sint,
                                                    float scale) {
  int idx = blockIdx.x * 256 + threadIdx.x;
  int d = idx & 63;
  int rest = idx >> 6;
  int h = rest % nheads;
  int bt = rest / nheads;
  int t = bt & (T - 1);
  unsigned short* p = buf + (size_t)bt * nheads * 128 + h * 128;
  float cc = cost[t * 64 + d], ss = sint[t * 64 + d];
  float x0 = bf2f(p[d]), x1 = bf2f(p[d + 64]);
  p[d]      = f2bf((x0 * cc - x1 * ss) * scale);
  p[d + 64] = f2bf((x1 * cc + x0 * ss) * scale);
}

// --- V transpose: vb16 (B*T, 512) -> vtb [b][kvh][128 d][2048 t] -----------
__global__ __launch_bounds__(256) void transpose_v(const unsigned short* __restrict__ vb16,
                                                   unsigned short* __restrict__ vtb) {
  __shared__ unsigned short tile[32][33];
  int t0 = blockIdx.x * 32, d0 = blockIdx.y * 32, b = blockIdx.z;
  int tx = threadIdx.x & 31, ty = threadIdx.x >> 5;  // ty 0..7
#pragma unroll
  for (int i = 0; i < 4; ++i) {
    int t = ty + i * 8;
    tile[t][tx] = vb16[((size_t)(b * 2048 + t0 + t)) * 512 + d0 + tx];
  }
  __syncthreads();
#pragma unroll
  for (int i = 0; i < 4; ++i) {
    int d = ty + i * 8;
    int D = d0 + d;
    vtb[((size_t)((b * 4 + (D >> 7)) * 128 + (D & 127))) * 2048 + t0 + tx] = tile[tx][d];
  }
}

// --- MFMA flash attention --------------------------------------------------
// One wave per 16-query tile, KV tiles of 32.
// qb: (B*T,2048) bf16 (RoPE+scale applied); kb: (B*T,512) bf16 (RoPE applied);
// vtb: [b][kvh][128][2048] bf16; attob out: (B*T,2048) bf16.
__global__ __launch_bounds__(256) void attn_mfma(const unsigned short* __restrict__ qb,
                                                 const unsigned short* __restrict__ kb,
                                                 const unsigned short* __restrict__ vtb,
                                                 unsigned short* __restrict__ attob) {
  __shared__ unsigned short plds[4][16][32];
  int w = threadIdx.x >> 6, lane = threadIdx.x & 63;
  int gw = blockIdx.x * 4 + w;
  int qt = gw & 127;
  int bh = gw >> 7;
  int h = bh & 15, b = bh >> 4;
  int kvh = h >> 2;
  int q0 = qt * 16;
  int g = lane >> 4, c = lane & 15;

  const unsigned short* qrow = qb + ((size_t)(b * 2048 + q0 + c)) * 2048 + h * 128;
  bf16x8 qa[4];
#pragma unroll
  for (int kc = 0; kc < 4; ++kc)
    qa[kc] = *(const bf16x8*)(qrow + kc * 32 + g * 8);

  const unsigned short* kbase = kb + (size_t)b * 2048 * 512 + kvh * 128;
  const unsigned short* vtbase = vtb + (size_t)(b * 4 + kvh) * 128 * 2048;

  f32x4 o_acc[8];
#pragma unroll
  for (int ch = 0; ch < 8; ++ch) o_acc[ch] = (f32x4){0.f, 0.f, 0.f, 0.f};
  float m[4], l[4];
#pragma unroll
  for (int r = 0; r < 4; ++r) { m[r] = -INFINITY; l[r] = 0.f; }

  int nt = (q0 + 47) >> 5;
  for (int ti = 0; ti < nt; ++ti) {
    int k0 = ti * 32;
    f32x4 s0 = (f32x4){0.f, 0.f, 0.f, 0.f};
    f32x4 s1 = (f32x4){0.f, 0.f, 0.f, 0.f};
#pragma unroll
    for (int kc = 0; kc < 4; ++kc) {
      bf16x8 kf0 = *(const bf16x8*)(kbase + (size_t)(k0 + c) * 512 + kc * 32 + g * 8);
      bf16x8 kf1 = *(const bf16x8*)(kbase + (size_t)(k0 + 16 + c) * 512 + kc * 32 + g * 8);
      s0 = __builtin_amdgcn_mfma_f32_16x16x32_bf16(qa[kc], kf0, s0, 0, 0, 0);
      s1 = __builtin_amdgcn_mfma_f32_16x16x32_bf16(qa[kc], kf1, s1, 0, 0, 0);
    }
    bool guard = (k0 + 31 > q0);
#pragma unroll
    for (int r = 0; r < 4; ++r) {
      int qi = q0 + g * 4 + r;
      if (guard) {
        if (k0 + c > qi)      s0[r] = -INFINITY;
        if (k0 + 16 + c > qi) s1[r] = -INFINITY;
      }
      float tv = fmaxf(s0[r], s1[r]);
#pragma unroll
      for (int off = 1; off < 16; off <<= 1) tv = fmaxf(tv, __shfl_xor(tv, off));
      float mn = fmaxf(m[r], tv);
      float corr = __expf(m[r] - mn);
      m[r] = mn;
      float p0 = __expf(s0[r] - mn);
      float p1 = __expf(s1[r] - mn);
      float rs = p0 + p1;
#pragma unroll
      for (int off = 1; off < 16; off <<= 1) rs += __shfl_xor(rs, off);
      l[r] = l[r] * corr + rs;
#pragma unroll
      for (int ch = 0; ch < 8; ++ch) o_acc[ch][r] *= corr;
      plds[w][g * 4 + r][c]      = f2bf(p0);
      plds[w][g * 4 + r][16 + c] = f2bf(p1);
    }
    // PV: O[16q][128d] += P(16x32) @ V(32x128); V via transposed layout
    bf16x8 pa = *(const bf16x8*)(&plds[w][c][g * 8]);
#pragma unroll
    for (int ch = 0; ch < 8; ++ch) {
      bf16x8 vf = *(const bf16x8*)(vtbase + (size_t)(ch * 16 + c) * 2048 + k0 + g * 8);
      o_acc[ch] = __builtin_amdgcn_mfma_f32_16x16x32_bf16(pa, vf, o_acc[ch], 0, 0, 0);
    }
  }
#pragma unroll
  for (int r = 0; r < 4; ++r) {
    float inv = 1.f / l[r];
    int qi = q0 + g * 4 + r;
    unsigned short* orow = attob + ((size_t)(b * 2048 + qi)) * 2048 + h * 128;
#pragma unroll
    for (int ch = 0; ch < 8; ++ch) orow[ch * 16 + c] = f2bf(o_acc[ch][r] * inv);
  }
}

// ---------------------------------------------------------------------------
extern "C" void kernel_launch(void* const* d_in, const int* in_sizes, int n_in,
                              void* d_out, int out_size, void* d_ws, size_t ws_size,
                              hipStream_t stream) {
  const float* x   = (const float*)d_in[0];
  const float* wq  = (const float*)d_in[1];
  const float* wkv = (const float*)d_in[2];
  const float* wk  = (const float*)d_in[3];
  const float* wv  = (const float*)d_in[4];
  const float* wo  = (const float*)d_in[5];
  float* out = (float*)d_out;
  float* ws  = (float*)d_ws;

  const int B = 2, T = 2048, H = 2048, NH = 16, NKV = 4, LAT = 256, KVD = 512;
  const int BT = B * T;  // 4096

  // bf16 workspace layout (counted in floats = 2 bf16)
  size_t off = 0;
  unsigned short* xb   = (unsigned short*)(ws + off); off += (size_t)BT * H / 2;     // 4M
  unsigned short* wqb  = (unsigned short*)(ws + off); off += (size_t)H * H / 2;      // 2M
  unsigned short* wkvb = (unsigned short*)(ws + off); off += (size_t)LAT * H / 2;    // 0.25M
  unsigned short* wkb  = (unsigned short*)(ws + off); off += (size_t)KVD * LAT / 2;  // 64K
  unsigned short* wvb  = (unsigned short*)(ws + off); off += (size_t)KVD * LAT / 2;  // 64K
  unsigned short* wob  = (unsigned short*)(ws + off); off += (size_t)H * H / 2;      // 2M
  unsigned short* qb   = (unsigned short*)(ws + off); off += (size_t)BT * H / 2;     // 4M
  unsigned short* kvlb = (unsigned short*)(ws + off); off += (size_t)BT * LAT / 2;   // 0.5M
  unsigned short* kb   = (unsigned short*)(ws + off); off += (size_t)BT * KVD / 2;   // 0.5M
  unsigned short* vb16 = (unsigned short*)(ws + off); off += (size_t)BT * KVD / 2;   // 0.5M
  unsigned short* vtb  = (unsigned short*)(ws + off); off += (size_t)BT * KVD / 2;   // 0.5M
  unsigned short* attob= (unsigned short*)(ws + off); off += (size_t)BT * H / 2;     // 4M
  float* cost = ws + off; off += (size_t)T * 64;
  float* sint = ws + off; off += (size_t)T * 64;
  // ~18.6M floats ~= 74.5 MiB

  const float scale = 0.088388347648318447f;  // 1/sqrt(128)

  rope_table<<<(T * 64 + 255) / 256, 256, 0, stream>>>(cost, sint, T);

  // fp32 -> bf16 converts
  conv_bf16<<<(BT * H / 4) / 256, 256, 0, stream>>>(x, xb, BT * H);
  conv_bf16<<<(H * H / 4) / 256, 256, 0, stream>>>(wq, wqb, H * H);
  conv_bf16<<<(LAT * H / 4) / 256, 256, 0, stream>>>(wkv, wkvb, LAT * H);
  conv_bf16<<<(KVD * LAT / 4) / 256, 256, 0, stream>>>(wk, wkb, KVD * LAT);
  conv_bf16<<<(KVD * LAT / 4) / 256, 256, 0, stream>>>(wv, wvb, KVD * LAT);
  conv_bf16<<<(H * H / 4) / 256, 256, 0, stream>>>(wo, wob, H * H);

  // Projections (bf16 MFMA, bf16 out)
  gemm_mfma<true><<<dim3(H / 128, BT / 128), 256, 0, stream>>>(xb, wqb, qb, BT, H, H);
  gemm_mfma<true><<<dim3(LAT / 128, BT / 128), 256, 0, stream>>>(xb, wkvb, kvlb, BT, LAT, H);
  gemm_mfma<true><<<dim3(KVD / 128, BT / 128), 256, 0, stream>>>(kvlb, wkb, kb, BT, KVD, LAT);
  gemm_mfma<true><<<dim3(KVD / 128, BT / 128), 256, 0, stream>>>(kvlb, wvb, vb16, BT, KVD, LAT);

  // RoPE in place (scale folded into q)
  rope_ip_bf16<<<(BT * NH * 64) / 256, 256, 0, stream>>>(qb, NH, T, cost, sint, scale);
  rope_ip_bf16<<<(BT * NKV * 64) / 256, 256, 0, stream>>>(kb, NKV, T, cost, sint, 1.0f);

  // V transpose to [b][kvh][d][t]
  transpose_v<<<dim3(T / 32, KVD / 32, B), 256, 0, stream>>>(vb16, vtb);

  // Flash attention (bf16 out)
  attn_mfma<<<(B * NH * T / 16) / 4, 256, 0, stream>>>(qb, kb, vtb, attob);

  // Output projection (fp32 out)
  gemm_mfma<false><<<dim3(H / 128, BT / 128), 256, 0, stream>>>(attob, wob, out, BT, H, H);
}

// Round 7
// 463.079 us; speedup vs baseline: 13.4063x; 1.6345x over previous
//
#include <hip/hip_runtime.h>
#include <math.h>

// ---------------------------------------------------------------------------
// DeepSeek MLHA attention. Round 5 (2nd resubmit; container outage x2):
// pipelined flash attention (K/V register prefetch, balanced blocks,
// defer-max). GEMMs unchanged.
// B=2, T=2048, hidden=2048, NH=16, NKV=4, HD=128, latent=256, kv_dim=512.
// ---------------------------------------------------------------------------

#define AS1 __attribute__((address_space(1)))
#define AS3 __attribute__((address_space(3)))

typedef short bf16x8 __attribute__((ext_vector_type(8)));
typedef float f32x4 __attribute__((ext_vector_type(4)));

__device__ __forceinline__ unsigned short f2bf(float x) {
  union { float f; unsigned int u; } q; q.f = x;
  unsigned int u = q.u;
  u += 0x7FFFu + ((u >> 16) & 1u);   // RNE
  return (unsigned short)(u >> 16);
}
__device__ __forceinline__ float bf2f(unsigned short x) {
  union { unsigned int u; float f; } q; q.u = ((unsigned int)x) << 16;
  return q.f;
}

// --- RoPE cos/sin table: (T, 64) each, double precision ---------------------
__global__ __launch_bounds__(256) void rope_table(float* __restrict__ cost,
                                                  float* __restrict__ sint,
                                                  int T) {
  int idx = blockIdx.x * 256 + threadIdx.x;
  if (idx >= T * 64) return;
  int t = idx >> 6, j = idx & 63;
  double invf = pow(10000.0, -(double)j / 64.0);
  double ang = (double)t * invf;
  cost[idx] = (float)cos(ang);
  sint[idx] = (float)sin(ang);
}

// --- fp32 -> bf16 convert (n multiple of 4) --------------------------------
__global__ __launch_bounds__(256) void conv_bf16(const float* __restrict__ src,
                                                 unsigned short* __restrict__ dst,
                                                 int n) {
  int i = (blockIdx.x * 256 + threadIdx.x) * 4;
  if (i >= n) return;
  float4 f = *(const float4*)(src + i);
  ushort4 o;
  o.x = f2bf(f.x); o.y = f2bf(f.y); o.z = f2bf(f.z); o.w = f2bf(f.w);
  *(ushort4*)(dst + i) = o;
}

// --- bf16 MFMA NT-GEMM: C[M,N] = A[M,K] @ W[N,K]^T (fp32 accum) ------------
template <bool OUT_BF16>
__global__ __launch_bounds__(256) void gemm_mfma(const unsigned short* __restrict__ A,
                                                 const unsigned short* __restrict__ W,
                                                 void* __restrict__ Cv,
                                                 int M, int N, int K) {
  __shared__ unsigned short Asl[128 * 32];
  __shared__ unsigned short Wsl[128 * 32];
  int tid = threadIdx.x;
  int w = tid >> 6, lane = tid & 63;
  int g = lane >> 4, c = lane & 15;
  int wm = w >> 1, wn = w & 1;
  int m0 = blockIdx.y * 128, n0 = blockIdx.x * 128;

  f32x4 acc[4][4] = {};

  for (int k0 = 0; k0 < K; k0 += 32) {
#pragma unroll
    for (int i = 0; i < 2; ++i) {
      int idx = i * 256 + tid;
      int row = idx >> 2;
      int kk = (idx & 3) * 8;
      __builtin_amdgcn_global_load_lds(
          (const AS1 void*)(A + (size_t)(m0 + row) * K + k0 + kk),
          (AS3 void*)(Asl + ((size_t)i * 256 + (w << 6)) * 8), 16, 0, 0);
      __builtin_amdgcn_global_load_lds(
          (const AS1 void*)(W + (size_t)(n0 + row) * K + k0 + kk),
          (AS3 void*)(Wsl + ((size_t)i * 256 + (w << 6)) * 8), 16, 0, 0);
    }
    __syncthreads();
    bf16x8 af[4], wf[4];
#pragma unroll
    for (int mi = 0; mi < 4; ++mi)
      af[mi] = *(const bf16x8*)(Asl + (wm * 64 + mi * 16 + c) * 32 + g * 8);
#pragma unroll
    for (int ni = 0; ni < 4; ++ni)
      wf[ni] = *(const bf16x8*)(Wsl + (wn * 64 + ni * 16 + c) * 32 + g * 8);
#pragma unroll
    for (int mi = 0; mi < 4; ++mi)
#pragma unroll
      for (int ni = 0; ni < 4; ++ni)
        acc[mi][ni] = __builtin_amdgcn_mfma_f32_16x16x32_bf16(af[mi], wf[ni],
                                                              acc[mi][ni], 0, 0, 0);
    __syncthreads();
  }
#pragma unroll
  for (int mi = 0; mi < 4; ++mi)
#pragma unroll
    for (int r = 0; r < 4; ++r) {
      size_t mrow = (size_t)(m0 + wm * 64 + mi * 16 + g * 4 + r) * N;
#pragma unroll
      for (int ni = 0; ni < 4; ++ni) {
        int n = n0 + wn * 64 + ni * 16 + c;
        if (OUT_BF16)
          ((unsigned short*)Cv)[mrow + n] = f2bf(acc[mi][ni][r]);
        else
          ((float*)Cv)[mrow + n] = acc[mi][ni][r];
      }
    }
}

// --- in-place RoPE on bf16 buffer (B*T, nheads*128), scale folded ----------
__global__ __launch_bounds__(256) void rope_ip_bf16(unsigned short* __restrict__ buf,
                                                    int nheads, int T,
                                                    const float* __restrict__ cost,
                                                    const float* __restrict__ sint,
                                                    float scale) {
  int idx = blockIdx.x * 256 + threadIdx.x;
  int d = idx & 63;
  int rest = idx >> 6;
  int h = rest % nheads;
  int bt = rest / nheads;
  int t = bt & (T - 1);
  unsigned short* p = buf + (size_t)bt * nheads * 128 + h * 128;
  float cc = cost[t * 64 + d], ss = sint[t * 64 + d];
  float x0 = bf2f(p[d]), x1 = bf2f(p[d + 64]);
  p[d]      = f2bf((x0 * cc - x1 * ss) * scale);
  p[d + 64] = f2bf((x1 * cc + x0 * ss) * scale);
}

// --- V transpose: vb16 (B*T, 512) -> vtb [b][kvh][128 d][2048 t] -----------
__global__ __launch_bounds__(256) void transpose_v(const unsigned short* __restrict__ vb16,
                                                   unsigned short* __restrict__ vtb) {
  __shared__ unsigned short tile[32][33];
  int t0 = blockIdx.x * 32, d0 = blockIdx.y * 32, b = blockIdx.z;
  int tx = threadIdx.x & 31, ty = threadIdx.x >> 5;
#pragma unroll
  for (int i = 0; i < 4; ++i) {
    int t = ty + i * 8;
    tile[t][tx] = vb16[((size_t)(b * 2048 + t0 + t)) * 512 + d0 + tx];
  }
  __syncthreads();
#pragma unroll
  for (int i = 0; i < 4; ++i) {
    int d = ty + i * 8;
    int D = d0 + d;
    vtb[((size_t)((b * 4 + (D >> 7)) * 128 + (D & 127))) * 2048 + t0 + tx] = tile[tx][d];
  }
}

// --- MFMA flash attention, pipelined ---------------------------------------
// One wave per 16-query tile, KV tiles of 32 keys, K/V prefetched into regs.
// Block = 4 waves with qt {g, 127-g, 63-g, 64+g} -> uniform work per block.
__global__ __launch_bounds__(256) void attn_mfma(const unsigned short* __restrict__ qb,
                                                 const unsigned short* __restrict__ kb,
                                                 const unsigned short* __restrict__ vtb,
                                                 unsigned short* __restrict__ attob) {
  __shared__ unsigned short plds[4][16][32];
  int w = threadIdx.x >> 6, lane = threadIdx.x & 63;
  int bh = blockIdx.x & 31;       // 32 (b,h) streams
  int grp = blockIdx.x >> 5;      // 0..31
  int qt;
  if      (w == 0) qt = grp;
  else if (w == 1) qt = 127 - grp;
  else if (w == 2) qt = 63 - grp;
  else             qt = 64 + grp;
  int h = bh & 15, b = bh >> 4;
  int kvh = h >> 2;
  int q0 = qt * 16;
  int g = lane >> 4, c = lane & 15;

  const unsigned short* qrow = qb + ((size_t)(b * 2048 + q0 + c)) * 2048 + h * 128;
  bf16x8 qa[4];
#pragma unroll
  for (int kc = 0; kc < 4; ++kc)
    qa[kc] = *(const bf16x8*)(qrow + kc * 32 + g * 8);

  const unsigned short* kbase = kb + (size_t)b * 2048 * 512 + kvh * 128;
  const unsigned short* vtbase = vtb + (size_t)(b * 4 + kvh) * 128 * 2048;

  f32x4 o_acc[8];
#pragma unroll
  for (int ch = 0; ch < 8; ++ch) o_acc[ch] = (f32x4){0.f, 0.f, 0.f, 0.f};
  float m[4], l[4];
#pragma unroll
  for (int r = 0; r < 4; ++r) { m[r] = -INFINITY; l[r] = 0.f; }

  int nt = (q0 + 47) >> 5;

  // K/V fragment registers; rotated across iterations via SSA (no copies).
  bf16x8 kf[8], vf[8];
  // prologue: K tile 0
#pragma unroll
  for (int kc = 0; kc < 4; ++kc) {
    kf[kc]     = *(const bf16x8*)(kbase + (size_t)(c) * 512 + kc * 32 + g * 8);
    kf[4 + kc] = *(const bf16x8*)(kbase + (size_t)(16 + c) * 512 + kc * 32 + g * 8);
  }

  for (int ti = 0; ti < nt; ++ti) {
    int k0 = ti * 32;
    // ---- QK^T (consumes kf) ----
    f32x4 s0 = (f32x4){0.f, 0.f, 0.f, 0.f};
    f32x4 s1 = (f32x4){0.f, 0.f, 0.f, 0.f};
#pragma unroll
    for (int kc = 0; kc < 4; ++kc) {
      s0 = __builtin_amdgcn_mfma_f32_16x16x32_bf16(qa[kc], kf[kc], s0, 0, 0, 0);
      s1 = __builtin_amdgcn_mfma_f32_16x16x32_bf16(qa[kc], kf[4 + kc], s1, 0, 0, 0);
    }
    // ---- issue V loads (this tile) -- latency hidden under softmax ----
#pragma unroll
    for (int ch = 0; ch < 8; ++ch)
      vf[ch] = *(const bf16x8*)(vtbase + (size_t)(ch * 16 + c) * 2048 + k0 + g * 8);
    // ---- issue K loads (next tile) ----
    if (ti + 1 < nt) {
      int k1 = k0 + 32;
#pragma unroll
      for (int kc = 0; kc < 4; ++kc) {
        kf[kc]     = *(const bf16x8*)(kbase + (size_t)(k1 + c) * 512 + kc * 32 + g * 8);
        kf[4 + kc] = *(const bf16x8*)(kbase + (size_t)(k1 + 16 + c) * 512 + kc * 32 + g * 8);
      }
    }
    // ---- causal mask + row maxes ----
    bool guard = (k0 + 31 > q0);
    float tv[4];
#pragma unroll
    for (int r = 0; r < 4; ++r) {
      int qi = q0 + g * 4 + r;
      if (guard) {
        if (k0 + c > qi)      s0[r] = -INFINITY;
        if (k0 + 16 + c > qi) s1[r] = -INFINITY;
      }
      float t = fmaxf(s0[r], s1[r]);
#pragma unroll
      for (int off = 1; off < 16; off <<= 1) t = fmaxf(t, __shfl_xor(t, off));
      tv[r] = t;
    }
    // ---- defer-max: skip rescale when no row max grew ----
    bool ok = (tv[0] <= m[0]) & (tv[1] <= m[1]) & (tv[2] <= m[2]) & (tv[3] <= m[3]);
    if (!__all(ok)) {
#pragma unroll
      for (int r = 0; r < 4; ++r) {
        float mn = fmaxf(m[r], tv[r]);
        float corr = __expf(m[r] - mn);
        l[r] *= corr;
#pragma unroll
        for (int ch = 0; ch < 8; ++ch) o_acc[ch][r] *= corr;
        m[r] = mn;
      }
    }
    // ---- P = exp(S - m), row sums, stage to LDS ----
#pragma unroll
    for (int r = 0; r < 4; ++r) {
      float p0 = __expf(s0[r] - m[r]);
      float p1 = __expf(s1[r] - m[r]);
      float rs = p0 + p1;
#pragma unroll
      for (int off = 1; off < 16; off <<= 1) rs += __shfl_xor(rs, off);
      l[r] += rs;
      plds[w][g * 4 + r][c]      = f2bf(p0);
      plds[w][g * 4 + r][16 + c] = f2bf(p1);
    }
    // ---- PV (consumes vf) ----
    bf16x8 pa = *(const bf16x8*)(&plds[w][c][g * 8]);
#pragma unroll
    for (int ch = 0; ch < 8; ++ch)
      o_acc[ch] = __builtin_amdgcn_mfma_f32_16x16x32_bf16(pa, vf[ch], o_acc[ch], 0, 0, 0);
  }
  // ---- epilogue ----
#pragma unroll
  for (int r = 0; r < 4; ++r) {
    float inv = 1.f / l[r];
    int qi = q0 + g * 4 + r;
    unsigned short* orow = attob + ((size_t)(b * 2048 + qi)) * 2048 + h * 128;
#pragma unroll
    for (int ch = 0; ch < 8; ++ch) orow[ch * 16 + c] = f2bf(o_acc[ch][r] * inv);
  }
}

// ---------------------------------------------------------------------------
extern "C" void kernel_launch(void* const* d_in, const int* in_sizes, int n_in,
                              void* d_out, int out_size, void* d_ws, size_t ws_size,
                              hipStream_t stream) {
  const float* x   = (const float*)d_in[0];
  const float* wq  = (const float*)d_in[1];
  const float* wkv = (const float*)d_in[2];
  const float* wk  = (const float*)d_in[3];
  const float* wv  = (const float*)d_in[4];
  const float* wo  = (const float*)d_in[5];
  float* out = (float*)d_out;
  float* ws  = (float*)d_ws;

  const int B = 2, T = 2048, H = 2048, NH = 16, NKV = 4, LAT = 256, KVD = 512;
  const int BT = B * T;  // 4096

  size_t off = 0;
  unsigned short* xb   = (unsigned short*)(ws + off); off += (size_t)BT * H / 2;
  unsigned short* wqb  = (unsigned short*)(ws + off); off += (size_t)H * H / 2;
  unsigned short* wkvb = (unsigned short*)(ws + off); off += (size_t)LAT * H / 2;
  unsigned short* wkb  = (unsigned short*)(ws + off); off += (size_t)KVD * LAT / 2;
  unsigned short* wvb  = (unsigned short*)(ws + off); off += (size_t)KVD * LAT / 2;
  unsigned short* wob  = (unsigned short*)(ws + off); off += (size_t)H * H / 2;
  unsigned short* qb   = (unsigned short*)(ws + off); off += (size_t)BT * H / 2;
  unsigned short* kvlb = (unsigned short*)(ws + off); off += (size_t)BT * LAT / 2;
  unsigned short* kb   = (unsigned short*)(ws + off); off += (size_t)BT * KVD / 2;
  unsigned short* vb16 = (unsigned short*)(ws + off); off += (size_t)BT * KVD / 2;
  unsigned short* vtb  = (unsigned short*)(ws + off); off += (size_t)BT * KVD / 2;
  unsigned short* attob= (unsigned short*)(ws + off); off += (size_t)BT * H / 2;
  float* cost = ws + off; off += (size_t)T * 64;
  float* sint = ws + off; off += (size_t)T * 64;

  const float scale = 0.088388347648318447f;  // 1/sqrt(128)

  rope_table<<<(T * 64 + 255) / 256, 256, 0, stream>>>(cost, sint, T);

  conv_bf16<<<(BT * H / 4) / 256, 256, 0, stream>>>(x, xb, BT * H);
  conv_bf16<<<(H * H / 4) / 256, 256, 0, stream>>>(wq, wqb, H * H);
  conv_bf16<<<(LAT * H / 4) / 256, 256, 0, stream>>>(wkv, wkvb, LAT * H);
  conv_bf16<<<(KVD * LAT / 4) / 256, 256, 0, stream>>>(wk, wkb, KVD * LAT);
  conv_bf16<<<(KVD * LAT / 4) / 256, 256, 0, stream>>>(wv, wvb, KVD * LAT);
  conv_bf16<<<(H * H / 4) / 256, 256, 0, stream>>>(wo, wob, H * H);

  gemm_mfma<true><<<dim3(H / 128, BT / 128), 256, 0, stream>>>(xb, wqb, qb, BT, H, H);
  gemm_mfma<true><<<dim3(LAT / 128, BT / 128), 256, 0, stream>>>(xb, wkvb, kvlb, BT, LAT, H);
  gemm_mfma<true><<<dim3(KVD / 128, BT / 128), 256, 0, stream>>>(kvlb, wkb, kb, BT, KVD, LAT);
  gemm_mfma<true><<<dim3(KVD / 128, BT / 128), 256, 0, stream>>>(kvlb, wvb, vb16, BT, KVD, LAT);

  rope_ip_bf16<<<(BT * NH * 64) / 256, 256, 0, stream>>>(qb, NH, T, cost, sint, scale);
  rope_ip_bf16<<<(BT * NKV * 64) / 256, 256, 0, stream>>>(kb, NKV, T, cost, sint, 1.0f);

  transpose_v<<<dim3(T / 32, KVD / 32, B), 256, 0, stream>>>(vb16, vtb);

  // Balanced pipelined attention: 32 bh * 32 groups = 1024 blocks, 4 waves each
  attn_mfma<<<1024, 256, 0, stream>>>(qb, kb, vtb, attob);

  gemm_mfma<false><<<dim3(H / 128, BT / 128), 256, 0, stream>>>(attob, wob, out, BT, H, H);
}

// Round 8
// 455.011 us; speedup vs baseline: 13.6440x; 1.0177x over previous
//
#include <hip/hip_runtime.h>
#include <math.h>

// ---------------------------------------------------------------------------
// DeepSeek MLHA attention. Round 8: swapped-QK^T softmax (lane-local k-reduce)
// + 1-wave attention blocks (slot backfill). GEMMs unchanged.
// B=2, T=2048, hidden=2048, NH=16, NKV=4, HD=128, latent=256, kv_dim=512.
// ---------------------------------------------------------------------------

#define AS1 __attribute__((address_space(1)))
#define AS3 __attribute__((address_space(3)))

typedef short bf16x8 __attribute__((ext_vector_type(8)));
typedef float f32x4 __attribute__((ext_vector_type(4)));

__device__ __forceinline__ unsigned short f2bf(float x) {
  union { float f; unsigned int u; } q; q.f = x;
  unsigned int u = q.u;
  u += 0x7FFFu + ((u >> 16) & 1u);   // RNE
  return (unsigned short)(u >> 16);
}
__device__ __forceinline__ float bf2f(unsigned short x) {
  union { unsigned int u; float f; } q; q.u = ((unsigned int)x) << 16;
  return q.f;
}
__device__ __forceinline__ unsigned int pack2bf(float a, float b) {
  return (unsigned int)f2bf(a) | ((unsigned int)f2bf(b) << 16);
}

// --- RoPE cos/sin table: (T, 64) each, double precision ---------------------
__global__ __launch_bounds__(256) void rope_table(float* __restrict__ cost,
                                                  float* __restrict__ sint,
                                                  int T) {
  int idx = blockIdx.x * 256 + threadIdx.x;
  if (idx >= T * 64) return;
  int t = idx >> 6, j = idx & 63;
  double invf = pow(10000.0, -(double)j / 64.0);
  double ang = (double)t * invf;
  cost[idx] = (float)cos(ang);
  sint[idx] = (float)sin(ang);
}

// --- fp32 -> bf16 convert (n multiple of 4) --------------------------------
__global__ __launch_bounds__(256) void conv_bf16(const float* __restrict__ src,
                                                 unsigned short* __restrict__ dst,
                                                 int n) {
  int i = (blockIdx.x * 256 + threadIdx.x) * 4;
  if (i >= n) return;
  float4 f = *(const float4*)(src + i);
  ushort4 o;
  o.x = f2bf(f.x); o.y = f2bf(f.y); o.z = f2bf(f.z); o.w = f2bf(f.w);
  *(ushort4*)(dst + i) = o;
}

// --- bf16 MFMA NT-GEMM: C[M,N] = A[M,K] @ W[N,K]^T (fp32 accum) ------------
template <bool OUT_BF16>
__global__ __launch_bounds__(256) void gemm_mfma(const unsigned short* __restrict__ A,
                                                 const unsigned short* __restrict__ W,
                                                 void* __restrict__ Cv,
                                                 int M, int N, int K) {
  __shared__ unsigned short Asl[128 * 32];
  __shared__ unsigned short Wsl[128 * 32];
  int tid = threadIdx.x;
  int w = tid >> 6, lane = tid & 63;
  int g = lane >> 4, c = lane & 15;
  int wm = w >> 1, wn = w & 1;
  int m0 = blockIdx.y * 128, n0 = blockIdx.x * 128;

  f32x4 acc[4][4] = {};

  for (int k0 = 0; k0 < K; k0 += 32) {
#pragma unroll
    for (int i = 0; i < 2; ++i) {
      int idx = i * 256 + tid;
      int row = idx >> 2;
      int kk = (idx & 3) * 8;
      __builtin_amdgcn_global_load_lds(
          (const AS1 void*)(A + (size_t)(m0 + row) * K + k0 + kk),
          (AS3 void*)(Asl + ((size_t)i * 256 + (w << 6)) * 8), 16, 0, 0);
      __builtin_amdgcn_global_load_lds(
          (const AS1 void*)(W + (size_t)(n0 + row) * K + k0 + kk),
          (AS3 void*)(Wsl + ((size_t)i * 256 + (w << 6)) * 8), 16, 0, 0);
    }
    __syncthreads();
    bf16x8 af[4], wf[4];
#pragma unroll
    for (int mi = 0; mi < 4; ++mi)
      af[mi] = *(const bf16x8*)(Asl + (wm * 64 + mi * 16 + c) * 32 + g * 8);
#pragma unroll
    for (int ni = 0; ni < 4; ++ni)
      wf[ni] = *(const bf16x8*)(Wsl + (wn * 64 + ni * 16 + c) * 32 + g * 8);
#pragma unroll
    for (int mi = 0; mi < 4; ++mi)
#pragma unroll
      for (int ni = 0; ni < 4; ++ni)
        acc[mi][ni] = __builtin_amdgcn_mfma_f32_16x16x32_bf16(af[mi], wf[ni],
                                                              acc[mi][ni], 0, 0, 0);
    __syncthreads();
  }
#pragma unroll
  for (int mi = 0; mi < 4; ++mi)
#pragma unroll
    for (int r = 0; r < 4; ++r) {
      size_t mrow = (size_t)(m0 + wm * 64 + mi * 16 + g * 4 + r) * N;
#pragma unroll
      for (int ni = 0; ni < 4; ++ni) {
        int n = n0 + wn * 64 + ni * 16 + c;
        if (OUT_BF16)
          ((unsigned short*)Cv)[mrow + n] = f2bf(acc[mi][ni][r]);
        else
          ((float*)Cv)[mrow + n] = acc[mi][ni][r];
      }
    }
}

// --- in-place RoPE on bf16 buffer (B*T, nheads*128), scale folded ----------
__global__ __launch_bounds__(256) void rope_ip_bf16(unsigned short* __restrict__ buf,
                                                    int nheads, int T,
                                                    const float* __restrict__ cost,
                                                    const float* __restrict__ sint,
                                                    float scale) {
  int idx = blockIdx.x * 256 + threadIdx.x;
  int d = idx & 63;
  int rest = idx >> 6;
  int h = rest % nheads;
  int bt = rest / nheads;
  int t = bt & (T - 1);
  unsigned short* p = buf + (size_t)bt * nheads * 128 + h * 128;
  float cc = cost[t * 64 + d], ss = sint[t * 64 + d];
  float x0 = bf2f(p[d]), x1 = bf2f(p[d + 64]);
  p[d]      = f2bf((x0 * cc - x1 * ss) * scale);
  p[d + 64] = f2bf((x1 * cc + x0 * ss) * scale);
}

// --- V transpose: vb16 (B*T, 512) -> vtb [b][kvh][128 d][2048 t] -----------
__global__ __launch_bounds__(256) void transpose_v(const unsigned short* __restrict__ vb16,
                                                   unsigned short* __restrict__ vtb) {
  __shared__ unsigned short tile[32][33];
  int t0 = blockIdx.x * 32, d0 = blockIdx.y * 32, b = blockIdx.z;
  int tx = threadIdx.x & 31, ty = threadIdx.x >> 5;
#pragma unroll
  for (int i = 0; i < 4; ++i) {
    int t = ty + i * 8;
    tile[t][tx] = vb16[((size_t)(b * 2048 + t0 + t)) * 512 + d0 + tx];
  }
  __syncthreads();
#pragma unroll
  for (int i = 0; i < 4; ++i) {
    int d = ty + i * 8;
    int D = d0 + d;
    vtb[((size_t)((b * 4 + (D >> 7)) * 128 + (D & 127))) * 2048 + t0 + tx] = tile[tx][d];
  }
}

// --- MFMA flash attention, swapped-QK^T softmax ----------------------------
// One wave (= one block) per 16-query tile. KV tiles of 32 keys.
// QK^T computed as mfma(K,Q): lane (g,c) holds S[k0+{g*4+r,16+g*4+r}][q0+c]
// -> k-reduce is 8 local values + shfl_xor(16) + shfl_xor(32).
// m,l per-lane scalars (q=q0+c). O stays in standard layout via LDS P-restage.
__global__ __launch_bounds__(64) void attn_mfma(const unsigned short* __restrict__ qb,
                                                const unsigned short* __restrict__ kb,
                                                const unsigned short* __restrict__ vtb,
                                                unsigned short* __restrict__ attob) {
  __shared__ unsigned short plds[16][32];
  int lane = threadIdx.x;
  int bid = blockIdx.x;
  int bh = bid & 31;              // 32 (b,h) streams
  int qt = 127 - (bid >> 5);      // longest work first
  int h = bh & 15, b = bh >> 4;
  int kvh = h >> 2;
  int q0 = qt * 16;
  int g = lane >> 4, c = lane & 15;

  const unsigned short* qrow = qb + ((size_t)(b * 2048 + q0 + c)) * 2048 + h * 128;
  bf16x8 qa[4];
#pragma unroll
  for (int kc = 0; kc < 4; ++kc)
    qa[kc] = *(const bf16x8*)(qrow + kc * 32 + g * 8);

  const unsigned short* kbase = kb + (size_t)b * 2048 * 512 + kvh * 128;
  const unsigned short* vtbase = vtb + (size_t)(b * 4 + kvh) * 128 * 2048;

  f32x4 o_acc[8];
#pragma unroll
  for (int ch = 0; ch < 8; ++ch) o_acc[ch] = (f32x4){0.f, 0.f, 0.f, 0.f};
  float m = -INFINITY, l = 0.f;   // for q = q0 + c (duplicated across g)

  int nt = (q0 + 47) >> 5;

  bf16x8 kf[8], vf[8];
#pragma unroll
  for (int kc = 0; kc < 4; ++kc) {
    kf[kc]     = *(const bf16x8*)(kbase + (size_t)(c) * 512 + kc * 32 + g * 8);
    kf[4 + kc] = *(const bf16x8*)(kbase + (size_t)(16 + c) * 512 + kc * 32 + g * 8);
  }

  for (int ti = 0; ti < nt; ++ti) {
    int k0 = ti * 32;
    // ---- swapped QK^T: s0[r]=S[k0+g*4+r][q0+c], s1[r]=S[k0+16+g*4+r][q0+c]
    f32x4 s0 = (f32x4){0.f, 0.f, 0.f, 0.f};
    f32x4 s1 = (f32x4){0.f, 0.f, 0.f, 0.f};
#pragma unroll
    for (int kc = 0; kc < 4; ++kc) {
      s0 = __builtin_amdgcn_mfma_f32_16x16x32_bf16(kf[kc], qa[kc], s0, 0, 0, 0);
      s1 = __builtin_amdgcn_mfma_f32_16x16x32_bf16(kf[4 + kc], qa[kc], s1, 0, 0, 0);
    }
    // ---- issue V loads (this tile): latency hides under softmax ----
#pragma unroll
    for (int ch = 0; ch < 8; ++ch)
      vf[ch] = *(const bf16x8*)(vtbase + (size_t)(ch * 16 + c) * 2048 + k0 + g * 8);
    // ---- issue K loads (next tile) ----
    if (ti + 1 < nt) {
      int k1 = k0 + 32;
#pragma unroll
      for (int kc = 0; kc < 4; ++kc) {
        kf[kc]     = *(const bf16x8*)(kbase + (size_t)(k1 + c) * 512 + kc * 32 + g * 8);
        kf[4 + kc] = *(const bf16x8*)(kbase + (size_t)(k1 + 16 + c) * 512 + kc * 32 + g * 8);
      }
    }
    // ---- causal mask (only near diagonal): k > q  <=>  kq + r > 0 ----
    if (k0 + 31 > q0) {
      int kq0 = k0 + g * 4 - (q0 + c);        // s0: k - q = kq0 + r
#pragma unroll
      for (int r = 0; r < 4; ++r) {
        if (kq0 + r > 0)      s0[r] = -INFINITY;
        if (kq0 + 16 + r > 0) s1[r] = -INFINITY;
      }
    }
    // ---- row max: 8 local + 2 shuffles ----
    float mx = fmaxf(fmaxf(fmaxf(s0[0], s0[1]), fmaxf(s0[2], s0[3])),
                     fmaxf(fmaxf(s1[0], s1[1]), fmaxf(s1[2], s1[3])));
    mx = fmaxf(mx, __shfl_xor(mx, 16));
    mx = fmaxf(mx, __shfl_xor(mx, 32));
    // ---- defer-max rescale (skipped when no row grew) ----
    if (__any(mx > m)) {
      float mn = fmaxf(m, mx);
      float corr = __expf(m - mn);
      l *= corr;
      // transpose corr to O-layout: row q = g*4+r  <- lane (g*4+r) holds q=c=g*4+r
#pragma unroll
      for (int r = 0; r < 4; ++r) {
        float corrT = __shfl(corr, g * 4 + r);
#pragma unroll
        for (int ch = 0; ch < 8; ++ch) o_acc[ch][r] *= corrT;
      }
      m = mn;
    }
    // ---- P = exp(S - m); row sum: 8 local + 2 shuffles ----
    float p00 = __expf(s0[0] - m), p01 = __expf(s0[1] - m);
    float p02 = __expf(s0[2] - m), p03 = __expf(s0[3] - m);
    float p10 = __expf(s1[0] - m), p11 = __expf(s1[1] - m);
    float p12 = __expf(s1[2] - m), p13 = __expf(s1[3] - m);
    float rs = ((p00 + p01) + (p02 + p03)) + ((p10 + p11) + (p12 + p13));
    rs += __shfl_xor(rs, 16);
    rs += __shfl_xor(rs, 32);
    l += rs;
    // ---- stage P to LDS: row q=c, cols k=g*4..g*4+3 and 16+g*4.. ----
    uint2 w0, w1;
    w0.x = pack2bf(p00, p01); w0.y = pack2bf(p02, p03);
    w1.x = pack2bf(p10, p11); w1.y = pack2bf(p12, p13);
    *(uint2*)(&plds[c][g * 4])      = w0;
    *(uint2*)(&plds[c][16 + g * 4]) = w1;
    // ---- PV: A-frag pa = P[q=c][g*8..g*8+7] ----
    bf16x8 pa = *(const bf16x8*)(&plds[c][g * 8]);
#pragma unroll
    for (int ch = 0; ch < 8; ++ch)
      o_acc[ch] = __builtin_amdgcn_mfma_f32_16x16x32_bf16(pa, vf[ch], o_acc[ch], 0, 0, 0);
  }
  // ---- epilogue: transpose l to O-layout, divide, store ----
#pragma unroll
  for (int r = 0; r < 4; ++r) {
    float lT = __shfl(l, g * 4 + r);
    float inv = 1.f / lT;
    int qi = q0 + g * 4 + r;
    unsigned short* orow = attob + ((size_t)(b * 2048 + qi)) * 2048 + h * 128;
#pragma unroll
    for (int ch = 0; ch < 8; ++ch) orow[ch * 16 + c] = f2bf(o_acc[ch][r] * inv);
  }
}

// ---------------------------------------------------------------------------
extern "C" void kernel_launch(void* const* d_in, const int* in_sizes, int n_in,
                              void* d_out, int out_size, void* d_ws, size_t ws_size,
                              hipStream_t stream) {
  const float* x   = (const float*)d_in[0];
  const float* wq  = (const float*)d_in[1];
  const float* wkv = (const float*)d_in[2];
  const float* wk  = (const float*)d_in[3];
  const float* wv  = (const float*)d_in[4];
  const float* wo  = (const float*)d_in[5];
  float* out = (float*)d_out;
  float* ws  = (float*)d_ws;

  const int B = 2, T = 2048, H = 2048, NH = 16, NKV = 4, LAT = 256, KVD = 512;
  const int BT = B * T;  // 4096

  size_t off = 0;
  unsigned short* xb   = (unsigned short*)(ws + off); off += (size_t)BT * H / 2;
  unsigned short* wqb  = (unsigned short*)(ws + off); off += (size_t)H * H / 2;
  unsigned short* wkvb = (unsigned short*)(ws + off); off += (size_t)LAT * H / 2;
  unsigned short* wkb  = (unsigned short*)(ws + off); off += (size_t)KVD * LAT / 2;
  unsigned short* wvb  = (unsigned short*)(ws + off); off += (size_t)KVD * LAT / 2;
  unsigned short* wob  = (unsigned short*)(ws + off); off += (size_t)H * H / 2;
  unsigned short* qb   = (unsigned short*)(ws + off); off += (size_t)BT * H / 2;
  unsigned short* kvlb = (unsigned short*)(ws + off); off += (size_t)BT * LAT / 2;
  unsigned short* kb   = (unsigned short*)(ws + off); off += (size_t)BT * KVD / 2;
  unsigned short* vb16 = (unsigned short*)(ws + off); off += (size_t)BT * KVD / 2;
  unsigned short* vtb  = (unsigned short*)(ws + off); off += (size_t)BT * KVD / 2;
  unsigned short* attob= (unsigned short*)(ws + off); off += (size_t)BT * H / 2;
  float* cost = ws + off; off += (size_t)T * 64;
  float* sint = ws + off; off += (size_t)T * 64;

  const float scale = 0.088388347648318447f;  // 1/sqrt(128)

  rope_table<<<(T * 64 + 255) / 256, 256, 0, stream>>>(cost, sint, T);

  conv_bf16<<<(BT * H / 4) / 256, 256, 0, stream>>>(x, xb, BT * H);
  conv_bf16<<<(H * H / 4) / 256, 256, 0, stream>>>(wq, wqb, H * H);
  conv_bf16<<<(LAT * H / 4) / 256, 256, 0, stream>>>(wkv, wkvb, LAT * H);
  conv_bf16<<<(KVD * LAT / 4) / 256, 256, 0, stream>>>(wk, wkb, KVD * LAT);
  conv_bf16<<<(KVD * LAT / 4) / 256, 256, 0, stream>>>(wv, wvb, KVD * LAT);
  conv_bf16<<<(H * H / 4) / 256, 256, 0, stream>>>(wo, wob, H * H);

  gemm_mfma<true><<<dim3(H / 128, BT / 128), 256, 0, stream>>>(xb, wqb, qb, BT, H, H);
  gemm_mfma<true><<<dim3(LAT / 128, BT / 128), 256, 0, stream>>>(xb, wkvb, kvlb, BT, LAT, H);
  gemm_mfma<true><<<dim3(KVD / 128, BT / 128), 256, 0, stream>>>(kvlb, wkb, kb, BT, KVD, LAT);
  gemm_mfma<true><<<dim3(KVD / 128, BT / 128), 256, 0, stream>>>(kvlb, wvb, vb16, BT, KVD, LAT);

  rope_ip_bf16<<<(BT * NH * 64) / 256, 256, 0, stream>>>(qb, NH, T, cost, sint, scale);
  rope_ip_bf16<<<(BT * NKV * 64) / 256, 256, 0, stream>>>(kb, NKV, T, cost, sint, 1.0f);

  transpose_v<<<dim3(T / 32, KVD / 32, B), 256, 0, stream>>>(vb16, vtb);

  // 4096 one-wave blocks (32 bh-streams x 128 q-tiles), longest first
  attn_mfma<<<4096, 64, 0, stream>>>(qb, kb, vtb, attob);

  gemm_mfma<false><<<dim3(H / 128, BT / 128), 256, 0, stream>>>(attob, wob, out, BT, H, H);
}

// Round 9
// 341.726 us; speedup vs baseline: 18.1671x; 1.3315x over previous
//
#include <hip/hip_runtime.h>
#include <math.h>

// ---------------------------------------------------------------------------
// DeepSeek MLHA attention. Round 9: LDS-shared K/V flash attention
// (4-wave blocks, double-buffered swizzled LDS, balanced grid, setprio).
// B=2, T=2048, hidden=2048, NH=16, NKV=4, HD=128, latent=256, kv_dim=512.
// ---------------------------------------------------------------------------

#define AS1 __attribute__((address_space(1)))
#define AS3 __attribute__((address_space(3)))

typedef short bf16x8 __attribute__((ext_vector_type(8)));
typedef float f32x4 __attribute__((ext_vector_type(4)));

__device__ __forceinline__ unsigned short f2bf(float x) {
  union { float f; unsigned int u; } q; q.f = x;
  unsigned int u = q.u;
  u += 0x7FFFu + ((u >> 16) & 1u);   // RNE
  return (unsigned short)(u >> 16);
}
__device__ __forceinline__ float bf2f(unsigned short x) {
  union { unsigned int u; float f; } q; q.u = ((unsigned int)x) << 16;
  return q.f;
}
__device__ __forceinline__ unsigned int pack2bf(float a, float b) {
  return (unsigned int)f2bf(a) | ((unsigned int)f2bf(b) << 16);
}

// 16B-granular XOR swizzles (write and read use the SAME involution)
__device__ __forceinline__ int swzK(int row, int ch) {   // K tile [32][128] bf16
  return (((row << 8) + (ch << 4)) ^ ((row & 7) << 4)) >> 1;  // short index
}
__device__ __forceinline__ int swzV(int row, int ch) {   // V^T tile [128][32] bf16
  return (((row << 6) + (ch << 4)) ^ ((row & 7) << 4)) >> 1;
}

// --- RoPE cos/sin table: (T, 64) each, double precision ---------------------
__global__ __launch_bounds__(256) void rope_table(float* __restrict__ cost,
                                                  float* __restrict__ sint,
                                                  int T) {
  int idx = blockIdx.x * 256 + threadIdx.x;
  if (idx >= T * 64) return;
  int t = idx >> 6, j = idx & 63;
  double invf = pow(10000.0, -(double)j / 64.0);
  double ang = (double)t * invf;
  cost[idx] = (float)cos(ang);
  sint[idx] = (float)sin(ang);
}

// --- fp32 -> bf16 convert (n multiple of 4) --------------------------------
__global__ __launch_bounds__(256) void conv_bf16(const float* __restrict__ src,
                                                 unsigned short* __restrict__ dst,
                                                 int n) {
  int i = (blockIdx.x * 256 + threadIdx.x) * 4;
  if (i >= n) return;
  float4 f = *(const float4*)(src + i);
  ushort4 o;
  o.x = f2bf(f.x); o.y = f2bf(f.y); o.z = f2bf(f.z); o.w = f2bf(f.w);
  *(ushort4*)(dst + i) = o;
}

// --- bf16 MFMA NT-GEMM: C[M,N] = A[M,K] @ W[N,K]^T (fp32 accum) ------------
template <bool OUT_BF16>
__global__ __launch_bounds__(256) void gemm_mfma(const unsigned short* __restrict__ A,
                                                 const unsigned short* __restrict__ W,
                                                 void* __restrict__ Cv,
                                                 int M, int N, int K) {
  __shared__ unsigned short Asl[128 * 32];
  __shared__ unsigned short Wsl[128 * 32];
  int tid = threadIdx.x;
  int w = tid >> 6, lane = tid & 63;
  int g = lane >> 4, c = lane & 15;
  int wm = w >> 1, wn = w & 1;
  int m0 = blockIdx.y * 128, n0 = blockIdx.x * 128;

  f32x4 acc[4][4] = {};

  for (int k0 = 0; k0 < K; k0 += 32) {
#pragma unroll
    for (int i = 0; i < 2; ++i) {
      int idx = i * 256 + tid;
      int row = idx >> 2;
      int kk = (idx & 3) * 8;
      __builtin_amdgcn_global_load_lds(
          (const AS1 void*)(A + (size_t)(m0 + row) * K + k0 + kk),
          (AS3 void*)(Asl + ((size_t)i * 256 + (w << 6)) * 8), 16, 0, 0);
      __builtin_amdgcn_global_load_lds(
          (const AS1 void*)(W + (size_t)(n0 + row) * K + k0 + kk),
          (AS3 void*)(Wsl + ((size_t)i * 256 + (w << 6)) * 8), 16, 0, 0);
    }
    __syncthreads();
    bf16x8 af[4], wf[4];
#pragma unroll
    for (int mi = 0; mi < 4; ++mi)
      af[mi] = *(const bf16x8*)(Asl + (wm * 64 + mi * 16 + c) * 32 + g * 8);
#pragma unroll
    for (int ni = 0; ni < 4; ++ni)
      wf[ni] = *(const bf16x8*)(Wsl + (wn * 64 + ni * 16 + c) * 32 + g * 8);
#pragma unroll
    for (int mi = 0; mi < 4; ++mi)
#pragma unroll
      for (int ni = 0; ni < 4; ++ni)
        acc[mi][ni] = __builtin_amdgcn_mfma_f32_16x16x32_bf16(af[mi], wf[ni],
                                                              acc[mi][ni], 0, 0, 0);
    __syncthreads();
  }
#pragma unroll
  for (int mi = 0; mi < 4; ++mi)
#pragma unroll
    for (int r = 0; r < 4; ++r) {
      size_t mrow = (size_t)(m0 + wm * 64 + mi * 16 + g * 4 + r) * N;
#pragma unroll
      for (int ni = 0; ni < 4; ++ni) {
        int n = n0 + wn * 64 + ni * 16 + c;
        if (OUT_BF16)
          ((unsigned short*)Cv)[mrow + n] = f2bf(acc[mi][ni][r]);
        else
          ((float*)Cv)[mrow + n] = acc[mi][ni][r];
      }
    }
}

// --- in-place RoPE on bf16 buffer (B*T, nheads*128), scale folded ----------
__global__ __launch_bounds__(256) void rope_ip_bf16(unsigned short* __restrict__ buf,
                                                    int nheads, int T,
                                                    const float* __restrict__ cost,
                                                    const float* __restrict__ sint,
                                                    float scale) {
  int idx = blockIdx.x * 256 + threadIdx.x;
  int d = idx & 63;
  int rest = idx >> 6;
  int h = rest % nheads;
  int bt = rest / nheads;
  int t = bt & (T - 1);
  unsigned short* p = buf + (size_t)bt * nheads * 128 + h * 128;
  float cc = cost[t * 64 + d], ss = sint[t * 64 + d];
  float x0 = bf2f(p[d]), x1 = bf2f(p[d + 64]);
  p[d]      = f2bf((x0 * cc - x1 * ss) * scale);
  p[d + 64] = f2bf((x1 * cc + x0 * ss) * scale);
}

// --- V transpose: vb16 (B*T, 512) -> vtb [b][kvh][128 d][2048 t] -----------
__global__ __launch_bounds__(256) void transpose_v(const unsigned short* __restrict__ vb16,
                                                   unsigned short* __restrict__ vtb) {
  __shared__ unsigned short tile[32][33];
  int t0 = blockIdx.x * 32, d0 = blockIdx.y * 32, b = blockIdx.z;
  int tx = threadIdx.x & 31, ty = threadIdx.x >> 5;
#pragma unroll
  for (int i = 0; i < 4; ++i) {
    int t = ty + i * 8;
    tile[t][tx] = vb16[((size_t)(b * 2048 + t0 + t)) * 512 + d0 + tx];
  }
  __syncthreads();
#pragma unroll
  for (int i = 0; i < 4; ++i) {
    int d = ty + i * 8;
    int D = d0 + d;
    vtb[((size_t)((b * 4 + (D >> 7)) * 128 + (D & 127))) * 2048 + t0 + tx] = tile[tx][d];
  }
}

// --- MFMA flash attention: 4-wave blocks, LDS-shared K/V -------------------
// Block = 4 waves = q-tiles {4j..4j+3} of one (b,h) stream.
// K tile (32 k x 128 d) and V^T tile (128 d x 32 k) double-buffered in LDS
// with 16B XOR swizzle; one barrier per K-tile; reg-staged async loads.
// Swapped QK^T softmax (lane-local k-reduce) as validated in round 8.
__global__ __launch_bounds__(256, 4) void attn_mfma(const unsigned short* __restrict__ qb,
                                                    const unsigned short* __restrict__ kb,
                                                    const unsigned short* __restrict__ vtb,
                                                    unsigned short* __restrict__ attob) {
  __shared__ unsigned short lds_k[2][4096];   // 2 x 8 KB
  __shared__ unsigned short lds_v[2][4096];   // 2 x 8 KB
  __shared__ unsigned short plds[4][16][40];  // padded: 2-way banks

  int tid = threadIdx.x;
  int w = tid >> 6, lane = tid & 63;
  int g = lane >> 4, c = lane & 15;

  int s = blockIdx.x & 31;
  int stream = blockIdx.x >> 5;
  int jj = (s & 1) ? (31 - (s >> 1)) : (s >> 1);  // balanced long/short pairing
  int h = stream & 15, b = stream >> 4;
  int kvh = h >> 2;
  int qt = 4 * jj + w;
  int q0 = qt * 16;
  int nt_own = (q0 + 47) >> 5;
  int nt_blk = 2 * jj + 2;                        // = nt of q-tile 4j+3

  // Q fragments (registers)
  const unsigned short* qrow = qb + ((size_t)(b * 2048 + q0 + c)) * 2048 + h * 128;
  bf16x8 qa[4];
#pragma unroll
  for (int kc = 0; kc < 4; ++kc)
    qa[kc] = *(const bf16x8*)(qrow + kc * 32 + g * 8);

  const unsigned short* kbase = kb + (size_t)b * 2048 * 512 + kvh * 128;
  const unsigned short* vtbase = vtb + (size_t)(b * 4 + kvh) * 128 * 2048;

  // staging thread mapping (whole block stages each tile cooperatively)
  int krow = tid & 31, kch = tid >> 5;   // K: row 0..31, chunk-pair 0..7
  int vd = tid >> 1, vh = tid & 1;       // V^T: row 0..127, chunk-pair 0..1

  f32x4 o_acc[8];
#pragma unroll
  for (int ch = 0; ch < 8; ++ch) o_acc[ch] = (f32x4){0.f, 0.f, 0.f, 0.f};
  float m = -INFINITY, l = 0.f;

  // ---- prologue: stage tile 0 into buf 0 ----
  {
    const unsigned short* gk = kbase + (size_t)krow * 512 + kch * 16;
    bf16x8 ka0 = *(const bf16x8*)gk;
    bf16x8 ka1 = *(const bf16x8*)(gk + 8);
    *(bf16x8*)&lds_k[0][swzK(krow, kch * 2)]     = ka0;
    *(bf16x8*)&lds_k[0][swzK(krow, kch * 2 + 1)] = ka1;
    const unsigned short* gv = vtbase + (size_t)vd * 2048 + vh * 16;
    bf16x8 va0 = *(const bf16x8*)gv;
    bf16x8 va1 = *(const bf16x8*)(gv + 8);
    *(bf16x8*)&lds_v[0][swzV(vd, vh * 2)]     = va0;
    *(bf16x8*)&lds_v[0][swzV(vd, vh * 2 + 1)] = va1;
  }
  __syncthreads();

  int cur = 0;
  for (int ti = 0; ti < nt_blk; ++ti) {
    int k0 = ti * 32;
    bool do_stage = (ti + 1 < nt_blk);
    bf16x8 ka0, ka1, va0, va1;
    if (do_stage) {   // issue next-tile loads early; latency hides under compute
      int k1 = k0 + 32;
      const unsigned short* gk = kbase + (size_t)(k1 + krow) * 512 + kch * 16;
      ka0 = *(const bf16x8*)gk;
      ka1 = *(const bf16x8*)(gk + 8);
      const unsigned short* gv = vtbase + (size_t)vd * 2048 + k1 + vh * 16;
      va0 = *(const bf16x8*)gv;
      va1 = *(const bf16x8*)(gv + 8);
    }
    if (ti < nt_own) {
      // ---- swapped QK^T from LDS ----
      f32x4 s0 = (f32x4){0.f, 0.f, 0.f, 0.f};
      f32x4 s1 = (f32x4){0.f, 0.f, 0.f, 0.f};
      __builtin_amdgcn_s_setprio(1);
#pragma unroll
      for (int kc = 0; kc < 4; ++kc) {
        bf16x8 kf0 = *(const bf16x8*)&lds_k[cur][swzK(c, kc * 4 + g)];
        bf16x8 kf1 = *(const bf16x8*)&lds_k[cur][swzK(16 + c, kc * 4 + g)];
        s0 = __builtin_amdgcn_mfma_f32_16x16x32_bf16(kf0, qa[kc], s0, 0, 0, 0);
        s1 = __builtin_amdgcn_mfma_f32_16x16x32_bf16(kf1, qa[kc], s1, 0, 0, 0);
      }
      __builtin_amdgcn_s_setprio(0);
      // ---- causal mask ----
      if (k0 + 31 > q0) {
        int kq0 = k0 + g * 4 - (q0 + c);
#pragma unroll
        for (int r = 0; r < 4; ++r) {
          if (kq0 + r > 0)      s0[r] = -INFINITY;
          if (kq0 + 16 + r > 0) s1[r] = -INFINITY;
        }
      }
      // ---- row max: 8 local + 2 shuffles ----
      float mx = fmaxf(fmaxf(fmaxf(s0[0], s0[1]), fmaxf(s0[2], s0[3])),
                       fmaxf(fmaxf(s1[0], s1[1]), fmaxf(s1[2], s1[3])));
      mx = fmaxf(mx, __shfl_xor(mx, 16));
      mx = fmaxf(mx, __shfl_xor(mx, 32));
      // ---- defer-max rescale ----
      if (__any(mx > m)) {
        float mn = fmaxf(m, mx);
        float corr = __expf(m - mn);
        l *= corr;
#pragma unroll
        for (int r = 0; r < 4; ++r) {
          float corrT = __shfl(corr, g * 4 + r);
#pragma unroll
          for (int ch = 0; ch < 8; ++ch) o_acc[ch][r] *= corrT;
        }
        m = mn;
      }
      // ---- P = exp(S - m); row sum ----
      float p00 = __expf(s0[0] - m), p01 = __expf(s0[1] - m);
      float p02 = __expf(s0[2] - m), p03 = __expf(s0[3] - m);
      float p10 = __expf(s1[0] - m), p11 = __expf(s1[1] - m);
      float p12 = __expf(s1[2] - m), p13 = __expf(s1[3] - m);
      float rs = ((p00 + p01) + (p02 + p03)) + ((p10 + p11) + (p12 + p13));
      rs += __shfl_xor(rs, 16);
      rs += __shfl_xor(rs, 32);
      l += rs;
      // ---- stage P (per-wave buffer, padded rows) ----
      uint2 w0, w1;
      w0.x = pack2bf(p00, p01); w0.y = pack2bf(p02, p03);
      w1.x = pack2bf(p10, p11); w1.y = pack2bf(p12, p13);
      *(uint2*)(&plds[w][c][g * 4])      = w0;
      *(uint2*)(&plds[w][c][16 + g * 4]) = w1;
      // ---- PV from LDS V^T ----
      bf16x8 pa = *(const bf16x8*)(&plds[w][c][g * 8]);
      __builtin_amdgcn_s_setprio(1);
#pragma unroll
      for (int ch = 0; ch < 8; ++ch) {
        bf16x8 vf = *(const bf16x8*)&lds_v[cur][swzV(ch * 16 + c, g)];
        o_acc[ch] = __builtin_amdgcn_mfma_f32_16x16x32_bf16(pa, vf, o_acc[ch], 0, 0, 0);
      }
      __builtin_amdgcn_s_setprio(0);
    }
    if (do_stage) {   // write-late: compiler inserts vmcnt wait here
      int nb = cur ^ 1;
      *(bf16x8*)&lds_k[nb][swzK(krow, kch * 2)]     = ka0;
      *(bf16x8*)&lds_k[nb][swzK(krow, kch * 2 + 1)] = ka1;
      *(bf16x8*)&lds_v[nb][swzV(vd, vh * 2)]     = va0;
      *(bf16x8*)&lds_v[nb][swzV(vd, vh * 2 + 1)] = va1;
    }
    __syncthreads();
    cur ^= 1;
  }
  // ---- epilogue ----
#pragma unroll
  for (int r = 0; r < 4; ++r) {
    float lT = __shfl(l, g * 4 + r);
    float inv = 1.f / lT;
    int qi = q0 + g * 4 + r;
    unsigned short* orow = attob + ((size_t)(b * 2048 + qi)) * 2048 + h * 128;
#pragma unroll
    for (int ch = 0; ch < 8; ++ch) orow[ch * 16 + c] = f2bf(o_acc[ch][r] * inv);
  }
}

// ---------------------------------------------------------------------------
extern "C" void kernel_launch(void* const* d_in, const int* in_sizes, int n_in,
                              void* d_out, int out_size, void* d_ws, size_t ws_size,
                              hipStream_t stream) {
  const float* x   = (const float*)d_in[0];
  const float* wq  = (const float*)d_in[1];
  const float* wkv = (const float*)d_in[2];
  const float* wk  = (const float*)d_in[3];
  const float* wv  = (const float*)d_in[4];
  const float* wo  = (const float*)d_in[5];
  float* out = (float*)d_out;
  float* ws  = (float*)d_ws;

  const int B = 2, T = 2048, H = 2048, NH = 16, NKV = 4, LAT = 256, KVD = 512;
  const int BT = B * T;  // 4096

  size_t off = 0;
  unsigned short* xb   = (unsigned short*)(ws + off); off += (size_t)BT * H / 2;
  unsigned short* wqb  = (unsigned short*)(ws + off); off += (size_t)H * H / 2;
  unsigned short* wkvb = (unsigned short*)(ws + off); off += (size_t)LAT * H / 2;
  unsigned short* wkb  = (unsigned short*)(ws + off); off += (size_t)KVD * LAT / 2;
  unsigned short* wvb  = (unsigned short*)(ws + off); off += (size_t)KVD * LAT / 2;
  unsigned short* wob  = (unsigned short*)(ws + off); off += (size_t)H * H / 2;
  unsigned short* qb   = (unsigned short*)(ws + off); off += (size_t)BT * H / 2;
  unsigned short* kvlb = (unsigned short*)(ws + off); off += (size_t)BT * LAT / 2;
  unsigned short* kb   = (unsigned short*)(ws + off); off += (size_t)BT * KVD / 2;
  unsigned short* vb16 = (unsigned short*)(ws + off); off += (size_t)BT * KVD / 2;
  unsigned short* vtb  = (unsigned short*)(ws + off); off += (size_t)BT * KVD / 2;
  unsigned short* attob= (unsigned short*)(ws + off); off += (size_t)BT * H / 2;
  float* cost = ws + off; off += (size_t)T * 64;
  float* sint = ws + off; off += (size_t)T * 64;

  const float scale = 0.088388347648318447f;  // 1/sqrt(128)

  rope_table<<<(T * 64 + 255) / 256, 256, 0, stream>>>(cost, sint, T);

  conv_bf16<<<(BT * H / 4) / 256, 256, 0, stream>>>(x, xb, BT * H);
  conv_bf16<<<(H * H / 4) / 256, 256, 0, stream>>>(wq, wqb, H * H);
  conv_bf16<<<(LAT * H / 4) / 256, 256, 0, stream>>>(wkv, wkvb, LAT * H);
  conv_bf16<<<(KVD * LAT / 4) / 256, 256, 0, stream>>>(wk, wkb, KVD * LAT);
  conv_bf16<<<(KVD * LAT / 4) / 256, 256, 0, stream>>>(wv, wvb, KVD * LAT);
  conv_bf16<<<(H * H / 4) / 256, 256, 0, stream>>>(wo, wob, H * H);

  gemm_mfma<true><<<dim3(H / 128, BT / 128), 256, 0, stream>>>(xb, wqb, qb, BT, H, H);
  gemm_mfma<true><<<dim3(LAT / 128, BT / 128), 256, 0, stream>>>(xb, wkvb, kvlb, BT, LAT, H);
  gemm_mfma<true><<<dim3(KVD / 128, BT / 128), 256, 0, stream>>>(kvlb, wkb, kb, BT, KVD, LAT);
  gemm_mfma<true><<<dim3(KVD / 128, BT / 128), 256, 0, stream>>>(kvlb, wvb, vb16, BT, KVD, LAT);

  rope_ip_bf16<<<(BT * NH * 64) / 256, 256, 0, stream>>>(qb, NH, T, cost, sint, scale);
  rope_ip_bf16<<<(BT * NKV * 64) / 256, 256, 0, stream>>>(kb, NKV, T, cost, sint, 1.0f);

  transpose_v<<<dim3(T / 32, KVD / 32, B), 256, 0, stream>>>(vb16, vtb);

  // 1024 blocks = 32 streams x 32 balanced q-groups, 4 waves each
  attn_mfma<<<1024, 256, 0, stream>>>(qb, kb, vtb, attob);

  gemm_mfma<false><<<dim3(H / 128, BT / 128), 256, 0, stream>>>(attob, wob, out, BT, H, H);
}